// Round 1
// baseline (125.691 us; speedup 1.0000x reference)
//
#include <hip/hip_runtime.h>
#include <math.h>

#define NTHREADS 512

// One block per (b,t). 8 waves: lane = channel hh, wave index = s-stride group.
__global__ __launch_bounds__(NTHREADS) void argaug_main(
    const float* __restrict__ x, const float* __restrict__ y,
    const int* __restrict__ mask,
    const float* __restrict__ W1, const float* __restrict__ b1,
    const float* __restrict__ W2, const float* __restrict__ b2,
    float* __restrict__ xf,          // d_out + 1, (256,64)
    double* __restrict__ psum, double* __restrict__ pcnt)
{
    __shared__ float  sW2[64 * 64];      // W2[o][h], row-major as given
    __shared__ float  wsAll[76 * 64];    // window values for current theta: [j][h]
    __shared__ float  sx[64], sy[64], sh[64], sb1[64], sb2[64];
    __shared__ int    ssrc[76];
    __shared__ double rsim[8][64];       // per-group best sim (reused as scratch later)
    __shared__ int    ridx[8][64];
    __shared__ double bestSim[64];
    __shared__ int    bestS[64], bestT[64];
    __shared__ double ssum[64];          // sum over h of chosen windows
    __shared__ double su[64];
    __shared__ double sred[2][64];
    __shared__ double qn_sh;

    const int tid = threadIdx.x;
    const int bt  = blockIdx.x;
    const int hh  = tid & 63;
    const int sg  = tid >> 6;

    for (int k = tid; k < 4096; k += NTHREADS) sW2[k] = W2[k];
    if (tid < 64) {
        sx[tid]  = x[bt * 64 + tid];
        sy[tid]  = y[bt * 64 + tid];
        sb1[tid] = b1[tid];
        sb2[tid] = b2[tid];
    }
    __syncthreads();

    if (tid < 64) {
        // h = fc1(x) * mask
        float acc = 0.0f;
        const float* w1r = W1 + tid * 64;
        for (int i = 0; i < 64; ++i) acc = fmaf(sx[i], w1r[i], acc);
        acc += sb1[tid];
        sh[tid] = acc * (float)mask[bt * 64 + tid];
        bestSim[tid] = -1.0e300;
        bestS[tid] = 0;
        bestT[tid] = 0;
    } else if (tid == 64) {
        double q = 0.0;
        for (int i = 0; i < 64; ++i) { double v = (double)sy[i]; q += v * v; }
        qn_sh = sqrt(q);
    }
    __syncthreads();

    const double qn = qn_sh;

    for (int t5 = 0; t5 < 5; ++t5) {
        // numpy linspace(0.8,1.2,5): y = start + i*((stop-start)/4), y[-1] = stop
        const double theta = (t5 == 4) ? 1.2 : (0.8 + (double)t5 * ((1.2 - 0.8) / 4.0));
        const int L = (int)floor(64.0 * theta);       // {51,57,64,70,76}
        const int S = L + 63;
        const double rcp = 64.0 / (double)L;          // O/L as numpy computes it

        if (tid < L) {
            int s0 = (int)floor((double)tid * rcp);   // nearest-interp src index
            ssrc[tid] = (s0 < 63) ? s0 : 63;
        }
        __syncthreads();
        // materialize window values for this theta: ws[j][h] = h[h]*W2[src[j],h] + b2[src[j]]
        for (int k = tid; k < L * 64; k += NTHREADS) {
            const int j = k >> 6, h2 = k & 63;
            const int sj = ssrc[j];
            wsAll[k] = sh[h2] * sW2[sj * 64 + h2] + sb2[sj];
        }
        __syncthreads();

        double bs = -1.0e300; int bi = 0x7fffffff;
        for (int s = sg; s < S; s += 8) {
            int jlo = s - 63; if (jlo < 0) jlo = 0;
            int jhi = s;      if (jhi > L - 1) jhi = L - 1;
            const int ioff = 63 - s;
            double dot0 = 0.0, dot1 = 0.0, ss0 = 0.0, ss1 = 0.0;
            int j = jlo;
            for (; j + 1 <= jhi; j += 2) {
                const double w0 = (double)wsAll[j * 64 + hh];
                const double y0 = (double)sy[j + ioff];
                const double w1v = (double)wsAll[(j + 1) * 64 + hh];
                const double y1 = (double)sy[j + 1 + ioff];
                dot0 = fma(w0, y0, dot0);
                ss0  = fma(w0, w0, ss0);
                dot1 = fma(w1v, y1, dot1);
                ss1  = fma(w1v, w1v, ss1);
            }
            if (j <= jhi) {
                const double w0 = (double)wsAll[j * 64 + hh];
                const double y0 = (double)sy[j + ioff];
                dot0 = fma(w0, y0, dot0);
                ss0  = fma(w0, w0, ss0);
            }
            const double dot = dot0 + dot1;
            const double ss2 = ss0 + ss1;
            const double denom = qn * sqrt(ss2);
            const double sim = (denom > 0.0) ? (dot / denom) : 0.0;
            if (sim > bs) { bs = sim; bi = s; }     // strict >: first max within stride
        }
        rsim[sg][hh] = bs;
        ridx[sg][hh] = bi;
        __syncthreads();
        if (tid < 64) {
            double m = rsim[0][tid]; int mi = ridx[0][tid];
            for (int g = 1; g < 8; ++g) {
                const double v = rsim[g][tid]; const int vi = ridx[g][tid];
                if (v > m || (v == m && vi < mi)) { m = v; mi = vi; }
            }
            // across thetas: strict < (earlier theta wins ties), like reference
            if (bestSim[tid] < m) { bestSim[tid] = m; bestS[tid] = mi; bestT[tid] = t5; }
        }
        __syncthreads();
    }

    // ---- materialize sum over h of the chosen windows ----
    {
        double accv = 0.0;
        for (int h2 = sg; h2 < 64; h2 += 8) {
            const int t5b = bestT[h2];
            const double theta = (t5b == 4) ? 1.2 : (0.8 + (double)t5b * ((1.2 - 0.8) / 4.0));
            const int L = (int)floor(64.0 * theta);
            const double rcp = 64.0 / (double)L;
            const int j = bestS[h2] - 63 + hh;       // hh = element index i here
            if (j >= 0 && j < L) {
                int sj = (int)floor((double)j * rcp);
                if (sj > 63) sj = 63;
                const float w = sh[h2] * sW2[sj * 64 + h2] + sb2[sj];
                accv += (double)w;
            }
        }
        rsim[sg][hh] = accv;   // reuse as scratch
    }
    __syncthreads();
    if (tid < 64) {
        double s0 = 0.0;
        for (int g = 0; g < 8; ++g) s0 += rsim[g][tid];
        ssum[tid] = s0;
    }
    __syncthreads();
    if (tid < 64) {
        // u = W1 * ssum + 64*b1   (sum over h of h2)
        double u = 64.0 * (double)sb1[tid];
        const float* w1r = W1 + tid * 64;
        for (int i = 0; i < 64; ++i) u += (double)w1r[i] * ssum[i];
        su[tid] = u;
    }
    __syncthreads();
    if (tid < 64) {
        // out = W2 * u + 64*b2
        double v = 64.0 * (double)sb2[tid];
        for (int j = 0; j < 64; ++j) v += (double)sW2[tid * 64 + j] * su[j];
        const float outf = (float)v;
        xf[bt * 64 + tid] = outf;
        const float yv = sy[tid];
        double pl = 0.0, pc = 0.0;
        if (yv != 0.0f) {
            const float d = outf - yv;
            pl = (double)(d * d);
            pc = 1.0;
        }
        sred[0][tid] = pl;
        sred[1][tid] = pc;
    }
    __syncthreads();
    if (tid == 0) {
        double a = 0.0, c = 0.0;
        for (int i = 0; i < 64; ++i) { a += sred[0][i]; c += sred[1][i]; }
        psum[bt] = a;
        pcnt[bt] = c;
    }
}

__global__ __launch_bounds__(256) void finalize_loss(
    const double* __restrict__ psum, const double* __restrict__ pcnt,
    float* __restrict__ out)
{
    __shared__ double a[256], c[256];
    const int t = threadIdx.x;
    a[t] = psum[t];
    c[t] = pcnt[t];
    __syncthreads();
    for (int s = 128; s > 0; s >>= 1) {
        if (t < s) { a[t] += a[t + s]; c[t] += c[t + s]; }
        __syncthreads();
    }
    if (t == 0) out[0] = (float)(a[0] / c[0]);
}

extern "C" void kernel_launch(void* const* d_in, const int* in_sizes, int n_in,
                              void* d_out, int out_size, void* d_ws, size_t ws_size,
                              hipStream_t stream) {
    const float* x    = (const float*)d_in[0];
    const float* y    = (const float*)d_in[1];
    const int*   mask = (const int*)d_in[2];
    const float* W1   = (const float*)d_in[3];
    const float* b1   = (const float*)d_in[4];
    const float* W2   = (const float*)d_in[5];
    const float* b2   = (const float*)d_in[6];
    float* out = (float*)d_out;

    double* psum = (double*)d_ws;
    double* pcnt = psum + 256;

    argaug_main<<<256, NTHREADS, 0, stream>>>(x, y, mask, W1, b1, W2, b2,
                                              out + 1, psum, pcnt);
    finalize_loss<<<1, 256, 0, stream>>>(psum, pcnt, out);
}

// Round 2
// 74.523 us; speedup vs baseline: 1.6866x; 1.6866x over previous
//
#include <hip/hip_runtime.h>
#include <math.h>

#define NT 1024
#define NW 16

// One block per (b,t). 16 waves; lane = channel hh; waves split the shift space
// into strips of 4 consecutive shifts (K=4 register reuse of window values).
__global__ __launch_bounds__(NT) void argaug_main(
    const float* __restrict__ x, const float* __restrict__ y,
    const int* __restrict__ mask,
    const float* __restrict__ W1, const float* __restrict__ b1,
    const float* __restrict__ W2, const float* __restrict__ b2,
    float* __restrict__ xf,          // d_out + 1, (256,64)
    double* __restrict__ psum, double* __restrict__ pcnt)
{
    __shared__ float  sW2[4096];        // W2[o][h] row-major
    __shared__ double Pbuf[77 * 64];    // prefix sums P[j][h], j=0..L ; aliased by rsim/ridx
    __shared__ double ypad[70];         // ypad[p]: p in [3,66] -> y[p-3], else 0
    __shared__ float  sx[64], sy[64], sh[64], sb1[64], sb2[64];
    __shared__ int2   sow[80];          // {src*64, bits(b2[src])} per j
    __shared__ double bestSim[64];
    __shared__ int    bestS[64], bestT[64];
    __shared__ double ssum64[64], su[64], sred[2][64];
    __shared__ double qn_sh;

    double* rsimB = Pbuf;                    // [NW*64] doubles  (bytes 0..8191)
    int*    ridxB = (int*)(Pbuf + NW * 64);  // [NW*64] ints     (bytes 8192..12287)

    const int tid = threadIdx.x;
    const int bt  = blockIdx.x;
    const int hh  = tid & 63;
    const int sg  = tid >> 6;

    for (int k = tid; k < 4096; k += NT) sW2[k] = W2[k];
    if (tid < 64) {
        sx[tid]  = x[bt * 64 + tid];
        sy[tid]  = y[bt * 64 + tid];
        sb1[tid] = b1[tid];
        sb2[tid] = b2[tid];
    }
    __syncthreads();

    if (tid < 64) {
        float acc = 0.0f;
        const float* w1r = W1 + tid * 64;
        for (int i = 0; i < 64; ++i) acc = fmaf(sx[i], w1r[i], acc);
        acc += sb1[tid];
        sh[tid] = acc * (float)mask[bt * 64 + tid];
        bestSim[tid] = -1.0e300;
        bestS[tid] = 0;
        bestT[tid] = 0;
    } else if (tid == 64) {
        double q = 0.0;
        for (int i = 0; i < 64; ++i) { double v = (double)sy[i]; q += v * v; }
        qn_sh = sqrt(q);
    } else if (tid >= 128 && tid < 198) {
        const int p = tid - 128;
        ypad[p] = (p >= 3 && p < 67) ? (double)sy[p - 3] : 0.0;
    }
    __syncthreads();

    const double qn = qn_sh;
    const float  shv = sh[hh];

    for (int t5 = 0; t5 < 5; ++t5) {
        const double theta = (t5 == 4) ? 1.2 : (0.8 + (double)t5 * ((1.2 - 0.8) / 4.0));
        const int L = (int)floor(64.0 * theta);   // {51,57,64,70,76}
        const int S = L + 63;
        const double rcp = 64.0 / (double)L;

        if (tid < L) {
            int s0 = (int)floor((double)tid * rcp);
            if (s0 > 63) s0 = 63;
            sow[tid] = make_int2(s0 * 64, __float_as_int(sb2[s0]));
        }
        __syncthreads();

        // f64 prefix sums of w^2 per channel (wave 0, serial in j)
        if (tid < 64) {
            const float sv = sh[tid];
            double run = 0.0;
            for (int j = 0; j < L; ++j) {
                const int2 ow = sow[j];
                const float wf = sv * sW2[ow.x + tid] + __int_as_float(ow.y);
                Pbuf[j * 64 + tid] = run;
                const double wd = (double)wf;
                run = fma(wd, wd, run);
            }
            Pbuf[L * 64 + tid] = run;
        }
        __syncthreads();

        double bs = -1.0e300; int bi = 0x7fffffff;
        for (int r = 0;; ++r) {
            const int q = sg + NW * r;
            const int s_first = 4 * q;
            if (s_first >= S) break;
            const int jstart = (s_first > 63) ? (s_first - 63) : 0;
            const int jend   = min(L - 1, s_first + 3);
            const int C      = 66 - s_first;          // ypad idx = j + C - k

            double dot0 = 0.0, dot1 = 0.0, dot2 = 0.0, dot3 = 0.0;
            double ym1 = ypad[jstart - 1 + C];
            double ym2 = ypad[jstart - 2 + C];
            double ym3 = ypad[jstart - 3 + C];
            #pragma unroll 4
            for (int j = jstart; j <= jend; ++j) {
                const int2 ow = sow[j];
                const float wf = shv * sW2[ow.x + hh] + __int_as_float(ow.y);
                const double w  = (double)wf;
                const double y0 = ypad[j + C];
                dot0 = fma(w, y0,  dot0);
                dot1 = fma(w, ym1, dot1);
                dot2 = fma(w, ym2, dot2);
                dot3 = fma(w, ym3, dot3);
                ym3 = ym2; ym2 = ym1; ym1 = y0;
            }

            #define DO_K(kk, dotk) { \
                const int s_k = s_first + kk; \
                if (s_k < S) { \
                    const int jlo = (s_k > 63) ? (s_k - 63) : 0; \
                    const int jhi = min(L - 1, s_k); \
                    const double ss = Pbuf[(jhi + 1) * 64 + hh] - Pbuf[jlo * 64 + hh]; \
                    const double denom = qn * sqrt(ss); \
                    const double sim = (denom > 0.0) ? (dotk / denom) : 0.0; \
                    if (sim > bs) { bs = sim; bi = s_k; } \
                } }
            DO_K(0, dot0)
            DO_K(1, dot1)
            DO_K(2, dot2)
            DO_K(3, dot3)
            #undef DO_K
        }
        __syncthreads();                 // all P reads complete before aliasing writes
        rsimB[sg * 64 + hh] = bs;
        ridxB[sg * 64 + hh] = bi;
        __syncthreads();
        if (tid < 64) {
            double m = rsimB[tid]; int mi = ridxB[tid];
            for (int g = 1; g < NW; ++g) {
                const double v = rsimB[g * 64 + tid]; const int vi = ridxB[g * 64 + tid];
                if (v > m || (v == m && vi < mi)) { m = v; mi = vi; }
            }
            if (bestSim[tid] < m) { bestSim[tid] = m; bestS[tid] = mi; bestT[tid] = t5; }
        }
        __syncthreads();
    }

    // ---- sum over h of the chosen windows (element index = hh) ----
    {
        double accv = 0.0;
        for (int h2 = sg; h2 < 64; h2 += NW) {
            const int t5b = bestT[h2];
            const double theta = (t5b == 4) ? 1.2 : (0.8 + (double)t5b * ((1.2 - 0.8) / 4.0));
            const int L = (int)floor(64.0 * theta);
            const double rcp = 64.0 / (double)L;
            const int j = bestS[h2] - 63 + hh;
            if (j >= 0 && j < L) {
                int sj = (int)floor((double)j * rcp);
                if (sj > 63) sj = 63;
                const float w = sh[h2] * sW2[sj * 64 + h2] + sb2[sj];
                accv += (double)w;
            }
        }
        rsimB[sg * 64 + hh] = accv;
    }
    __syncthreads();
    if (tid < 64) {
        double s0 = 0.0;
        for (int g = 0; g < NW; ++g) s0 += rsimB[g * 64 + tid];
        ssum64[tid] = s0;
    }
    __syncthreads();
    if (tid < 64) {
        double u = 64.0 * (double)sb1[tid];
        const float* w1r = W1 + tid * 64;
        for (int i = 0; i < 64; ++i) u += (double)w1r[i] * ssum64[i];
        su[tid] = u;
    }
    __syncthreads();
    if (tid < 64) {
        double v = 64.0 * (double)sb2[tid];
        for (int j = 0; j < 64; ++j) v += (double)sW2[tid * 64 + j] * su[j];
        const float outf = (float)v;
        xf[bt * 64 + tid] = outf;
        const float yv = sy[tid];
        double pl = 0.0, pc = 0.0;
        if (yv != 0.0f) {
            const float d = outf - yv;
            pl = (double)(d * d);
            pc = 1.0;
        }
        sred[0][tid] = pl;
        sred[1][tid] = pc;
    }
    __syncthreads();
    if (tid == 0) {
        double a = 0.0, c = 0.0;
        for (int i = 0; i < 64; ++i) { a += sred[0][i]; c += sred[1][i]; }
        psum[bt] = a;
        pcnt[bt] = c;
    }
}

__global__ __launch_bounds__(256) void finalize_loss(
    const double* __restrict__ psum, const double* __restrict__ pcnt,
    float* __restrict__ out)
{
    __shared__ double a[256], c[256];
    const int t = threadIdx.x;
    a[t] = psum[t];
    c[t] = pcnt[t];
    __syncthreads();
    for (int s = 128; s > 0; s >>= 1) {
        if (t < s) { a[t] += a[t + s]; c[t] += c[t + s]; }
        __syncthreads();
    }
    if (t == 0) out[0] = (float)(a[0] / c[0]);
}

extern "C" void kernel_launch(void* const* d_in, const int* in_sizes, int n_in,
                              void* d_out, int out_size, void* d_ws, size_t ws_size,
                              hipStream_t stream) {
    const float* x    = (const float*)d_in[0];
    const float* y    = (const float*)d_in[1];
    const int*   mask = (const int*)d_in[2];
    const float* W1   = (const float*)d_in[3];
    const float* b1   = (const float*)d_in[4];
    const float* W2   = (const float*)d_in[5];
    const float* b2   = (const float*)d_in[6];
    float* out = (float*)d_out;

    double* psum = (double*)d_ws;
    double* pcnt = psum + 256;

    argaug_main<<<256, NT, 0, stream>>>(x, y, mask, W1, b1, W2, b2,
                                        out + 1, psum, pcnt);
    finalize_loss<<<1, 256, 0, stream>>>(psum, pcnt, out);
}

// Round 3
// 53.376 us; speedup vs baseline: 2.3548x; 1.3962x over previous
//
#include <hip/hip_runtime.h>
#include <math.h>

#define NT 1024
#define NW 16

// One block per (b,t). 16 waves; lane = channel hh; each wave owns ONE strip
// of 9 consecutive shifts per theta (K=9 register reuse of window values).
__global__ __launch_bounds__(NT) void argaug_main(
    const float* __restrict__ x, const float* __restrict__ y,
    const int* __restrict__ mask,
    const float* __restrict__ W1, const float* __restrict__ b1,
    const float* __restrict__ W2, const float* __restrict__ b2,
    float* __restrict__ xf,          // d_out + 1, (256,64)
    double* __restrict__ psum, double* __restrict__ pcnt)
{
    __shared__ float  sW2[4096];       // W2[o][h] row-major
    __shared__ double wdBuf[76 * 64];  // f64 window values wd[j][h]; aliased by rsim/ridx
    __shared__ double ypad[80];        // ypad[p] = y[p-8] for p in [8,71], else 0
    __shared__ float  sx[64], sy[64], sh[64], sb1[64], sb2[64];
    __shared__ double bestSim[64];
    __shared__ int    bestS[64], bestT[64];
    __shared__ double ssum64[64], su[64], sred[2][64];
    __shared__ double qn_sh, iqn_sh;

    double* rsimB = wdBuf;                    // [NW*64] doubles (aliased, barrier-separated)
    int*    ridxB = (int*)(wdBuf + NW * 64);  // [NW*64] ints

    const int tid = threadIdx.x;
    const int bt  = blockIdx.x;
    const int hh  = tid & 63;
    const int sg  = tid >> 6;

    for (int k = tid; k < 4096; k += NT) sW2[k] = W2[k];
    if (tid < 64) {
        sx[tid]  = x[bt * 64 + tid];
        sy[tid]  = y[bt * 64 + tid];
        sb1[tid] = b1[tid];
        sb2[tid] = b2[tid];
    }
    __syncthreads();

    if (tid < 64) {
        float acc = 0.0f;
        const float* w1r = W1 + tid * 64;
        for (int i = 0; i < 64; ++i) acc = fmaf(sx[i], w1r[i], acc);
        acc += sb1[tid];
        sh[tid] = acc * (float)mask[bt * 64 + tid];
        bestSim[tid] = -1.0e300;
        bestS[tid] = 0;
        bestT[tid] = 0;
    } else if (tid == 64) {
        double q = 0.0;
        for (int i = 0; i < 64; ++i) { double v = (double)sy[i]; q += v * v; }
        const double qv = sqrt(q);
        qn_sh  = qv;
        iqn_sh = (qv > 0.0) ? (1.0 / qv) : 0.0;
    } else if (tid >= 128 && tid < 208) {
        const int p = tid - 128;
        ypad[p] = (p >= 8 && p < 72) ? (double)sy[p - 8] : 0.0;
    }
    __syncthreads();

    const double qn  = qn_sh;
    const double iqn = iqn_sh;

    for (int t5 = 0; t5 < 5; ++t5) {
        const double theta = (t5 == 4) ? 1.2 : (0.8 + (double)t5 * ((1.2 - 0.8) / 4.0));
        const int L = (int)floor(64.0 * theta);   // {51,57,64,70,76}
        const int S = L + 63;
        const double rcp = 64.0 / (double)L;

        // Phase A (parallel): wd[j][h] = (f64)(sh[h]*W2[src(j)][h] + b2[src(j)])
        for (int k = tid; k < L * 64; k += NT) {
            const int j = k >> 6, h = k & 63;     // j is wave-uniform
            int sj = (int)floor((double)j * rcp);
            if (sj > 63) sj = 63;
            const float wf = sh[h] * sW2[sj * 64 + h] + sb2[sj];
            wdBuf[k] = (double)wf;
        }
        __syncthreads();

        double bs = -1.0e300; int bi = 0x7fffffff;
        const int s_first = 9 * sg;
        if (s_first < S) {
            const int jstart = (s_first > 63) ? (s_first - 63) : 0;
            const int jmid   = (s_first < L - 1) ? s_first : (L - 1);
            const int jend   = (s_first + 8 < L - 1) ? (s_first + 8) : (L - 1);
            const int C      = 71 - s_first;      // ypad idx = j + C - k

            double d0=0,d1=0,d2=0,d3=0,d4=0,d5=0,d6=0,d7=0,d8=0,ssA=0;
            double ym1 = ypad[jstart + C - 1];
            double ym2 = ypad[jstart + C - 2];
            double ym3 = ypad[jstart + C - 3];
            double ym4 = ypad[jstart + C - 4];
            double ym5 = ypad[jstart + C - 5];
            double ym6 = ypad[jstart + C - 6];
            double ym7 = ypad[jstart + C - 7];
            double ym8 = ypad[jstart + C - 8];

            #pragma unroll 9
            for (int j = jstart; j <= jmid; ++j) {
                const double w  = wdBuf[j * 64 + hh];
                const double y0 = ypad[j + C];
                d0 = fma(w, y0,  d0); d1 = fma(w, ym1, d1); d2 = fma(w, ym2, d2);
                d3 = fma(w, ym3, d3); d4 = fma(w, ym4, d4); d5 = fma(w, ym5, d5);
                d6 = fma(w, ym6, d6); d7 = fma(w, ym7, d7); d8 = fma(w, ym8, d8);
                ssA = fma(w, w, ssA);
                ym8=ym7; ym7=ym6; ym6=ym5; ym5=ym4; ym4=ym3; ym3=ym2; ym2=ym1; ym1=y0;
            }
            #pragma unroll 9
            for (int j = jmid + 1; j <= jend; ++j) {   // <= 8 iters
                const double w  = wdBuf[j * 64 + hh];
                const double y0 = ypad[j + C];
                d0 = fma(w, y0,  d0); d1 = fma(w, ym1, d1); d2 = fma(w, ym2, d2);
                d3 = fma(w, ym3, d3); d4 = fma(w, ym4, d4); d5 = fma(w, ym5, d5);
                d6 = fma(w, ym6, d6); d7 = fma(w, ym7, d7); d8 = fma(w, ym8, d8);
                ym8=ym7; ym7=ym6; ym6=ym5; ym5=ym4; ym4=ym3; ym3=ym2; ym2=ym1; ym1=y0;
            }

            const int kmax = (S - s_first < 9) ? (S - s_first) : 9;
            double ss = ssA;
            #define SSUP(kk) { \
                const int jh = s_first + kk; \
                const int jl = s_first + kk - 64; \
                if (jh <= L - 1) { const double w = wdBuf[jh * 64 + hh]; ss = fma(w,  w, ss); } \
                if (jl >= 0)     { const double w = wdBuf[jl * 64 + hh]; ss = fma(-w, w, ss); } }
            #define EVALK(kk, dk) if (kk < kmax) { \
                double sim = 0.0; \
                if (ss > 0.0 && qn > 0.0) sim = dk * rsqrt(ss) * iqn; \
                if (sim > bs) { bs = sim; bi = s_first + kk; } }
            EVALK(0, d0)
            if (1 < kmax) { SSUP(1) EVALK(1, d1) }
            if (2 < kmax) { SSUP(2) EVALK(2, d2) }
            if (3 < kmax) { SSUP(3) EVALK(3, d3) }
            if (4 < kmax) { SSUP(4) EVALK(4, d4) }
            if (5 < kmax) { SSUP(5) EVALK(5, d5) }
            if (6 < kmax) { SSUP(6) EVALK(6, d6) }
            if (7 < kmax) { SSUP(7) EVALK(7, d7) }
            if (8 < kmax) { SSUP(8) EVALK(8, d8) }
            #undef SSUP
            #undef EVALK
        }
        __syncthreads();                 // selection reads of wdBuf complete
        rsimB[sg * 64 + hh] = bs;
        ridxB[sg * 64 + hh] = bi;
        __syncthreads();
        if (tid < 64) {
            double m = rsimB[tid]; int mi = ridxB[tid];
            for (int g = 1; g < NW; ++g) {
                const double v = rsimB[g * 64 + tid]; const int vi = ridxB[g * 64 + tid];
                if (v > m || (v == m && vi < mi)) { m = v; mi = vi; }
            }
            if (bestSim[tid] < m) { bestSim[tid] = m; bestS[tid] = mi; bestT[tid] = t5; }
        }
        __syncthreads();                 // reduce done before next Phase A overwrites alias
    }

    // ---- sum over h of the chosen windows (element index = hh) ----
    {
        double accv = 0.0;
        for (int h2 = sg; h2 < 64; h2 += NW) {
            const int t5b = bestT[h2];
            const double theta = (t5b == 4) ? 1.2 : (0.8 + (double)t5b * ((1.2 - 0.8) / 4.0));
            const int L = (int)floor(64.0 * theta);
            const double rcp = 64.0 / (double)L;
            const int j = bestS[h2] - 63 + hh;
            if (j >= 0 && j < L) {
                int sj = (int)floor((double)j * rcp);
                if (sj > 63) sj = 63;
                const float w = sh[h2] * sW2[sj * 64 + h2] + sb2[sj];
                accv += (double)w;
            }
        }
        rsimB[sg * 64 + hh] = accv;
    }
    __syncthreads();
    if (tid < 64) {
        double s0 = 0.0;
        for (int g = 0; g < NW; ++g) s0 += rsimB[g * 64 + tid];
        ssum64[tid] = s0;
    }
    __syncthreads();
    if (tid < 64) {
        double u = 64.0 * (double)sb1[tid];
        const float* w1r = W1 + tid * 64;
        for (int i = 0; i < 64; ++i) u += (double)w1r[i] * ssum64[i];
        su[tid] = u;
    }
    __syncthreads();
    if (tid < 64) {
        double v = 64.0 * (double)sb2[tid];
        for (int j = 0; j < 64; ++j) v += (double)sW2[tid * 64 + j] * su[j];
        const float outf = (float)v;
        xf[bt * 64 + tid] = outf;
        const float yv = sy[tid];
        double pl = 0.0, pc = 0.0;
        if (yv != 0.0f) {
            const float d = outf - yv;
            pl = (double)(d * d);
            pc = 1.0;
        }
        sred[0][tid] = pl;
        sred[1][tid] = pc;
    }
    __syncthreads();
    if (tid == 0) {
        double a = 0.0, c = 0.0;
        for (int i = 0; i < 64; ++i) { a += sred[0][i]; c += sred[1][i]; }
        psum[bt] = a;
        pcnt[bt] = c;
    }
}

__global__ __launch_bounds__(256) void finalize_loss(
    const double* __restrict__ psum, const double* __restrict__ pcnt,
    float* __restrict__ out)
{
    __shared__ double a[256], c[256];
    const int t = threadIdx.x;
    a[t] = psum[t];
    c[t] = pcnt[t];
    __syncthreads();
    for (int s = 128; s > 0; s >>= 1) {
        if (t < s) { a[t] += a[t + s]; c[t] += c[t + s]; }
        __syncthreads();
    }
    if (t == 0) out[0] = (float)(a[0] / c[0]);
}

extern "C" void kernel_launch(void* const* d_in, const int* in_sizes, int n_in,
                              void* d_out, int out_size, void* d_ws, size_t ws_size,
                              hipStream_t stream) {
    const float* x    = (const float*)d_in[0];
    const float* y    = (const float*)d_in[1];
    const int*   mask = (const int*)d_in[2];
    const float* W1   = (const float*)d_in[3];
    const float* b1   = (const float*)d_in[4];
    const float* W2   = (const float*)d_in[5];
    const float* b2   = (const float*)d_in[6];
    float* out = (float*)d_out;

    double* psum = (double*)d_ws;
    double* pcnt = psum + 256;

    argaug_main<<<256, NT, 0, stream>>>(x, y, mask, W1, b1, W2, b2,
                                        out + 1, psum, pcnt);
    finalize_loss<<<1, 256, 0, stream>>>(psum, pcnt, out);
}